// Round 1
// baseline (6378.543 us; speedup 1.0000x reference)
//
#include <hip/hip_runtime.h>
#include <float.h>

#define D_    768
#define GD    64
#define PD    256
#define HH    12
#define HDD   64
#define NGP   (GD*PD)   // 16384
#define SCALE 0.125f

// ---------------- GEMM: C[M,N] = A[M,K]*B[K,N] (+bias), row-major ----------------
// 64x64 tile, 256 threads, 4x4 microtile, K-tile 16.
template<int BIAS>
__global__ void gemm_k(const float* __restrict__ A, const float* __restrict__ B,
                       const float* __restrict__ bias, float* __restrict__ C,
                       int M, int N, int K) {
  __shared__ __align__(16) float As[16][68];  // As[k][m], pad 68 keeps float4 alignment, 2-way banks (free)
  __shared__ __align__(16) float Bs[16][68];  // Bs[k][n]
  const int tid = threadIdx.x;
  const int tx = tid & 15, ty = tid >> 4;
  const int m0 = blockIdx.y * 64, n0 = blockIdx.x * 64;
  const int arow = tid >> 2, akk = (tid & 3) * 4;   // A tile: 64 rows x 16 k
  const int brow = tid >> 4, bcol = (tid & 15) * 4; // B tile: 16 k x 64 n
  float acc[4][4] = {};
  for (int k0 = 0; k0 < K; k0 += 16) {
    float4 a4 = *(const float4*)(A + (size_t)(m0 + arow) * K + k0 + akk);
    float4 b4 = *(const float4*)(B + (size_t)(k0 + brow) * N + n0 + bcol);
    __syncthreads();   // previous iter's LDS reads must finish
    As[akk+0][arow] = a4.x; As[akk+1][arow] = a4.y;
    As[akk+2][arow] = a4.z; As[akk+3][arow] = a4.w;
    *(float4*)&Bs[brow][bcol] = b4;
    __syncthreads();
    #pragma unroll
    for (int k = 0; k < 16; ++k) {
      float4 av = *(const float4*)&As[k][ty*4];
      float4 bv = *(const float4*)&Bs[k][tx*4];
      float a[4] = {av.x, av.y, av.z, av.w};
      float b[4] = {bv.x, bv.y, bv.z, bv.w};
      #pragma unroll
      for (int i = 0; i < 4; ++i)
        #pragma unroll
        for (int j = 0; j < 4; ++j)
          acc[i][j] = fmaf(a[i], b[j], acc[i][j]);
    }
  }
  #pragma unroll
  for (int i = 0; i < 4; ++i) {
    float bv = BIAS ? bias[m0 + ty*4 + i] : 0.f;
    float4 o;
    o.x = acc[i][0] + bv; o.y = acc[i][1] + bv;
    o.z = acc[i][2] + bv; o.w = acc[i][3] + bv;
    *(float4*)(C + (size_t)(m0 + ty*4 + i) * N + n0 + tx*4) = o;
  }
}

// ---------------- Attention: one block per (g,h); thread t = query row p ----------------
// qkv layout (one batch): [3*768, 16384]; channel e = sel*768 + h*64 + hd; col = g*256 + p.
__global__ __launch_bounds__(256, 1)
void attn_k(const float* __restrict__ qkv, const unsigned char* __restrict__ mask,
            float* __restrict__ attn_out) {
  __shared__ float k_s[64][65];   // K chunk [q][hd], pad 65 -> conflict-free writes, broadcast reads
  __shared__ float v_s[64][65];
  const int g = blockIdx.x, h = blockIdx.y;
  const int t = threadIdx.x;  // p
  const size_t qb = (size_t)(h * HDD) * NGP + (size_t)g * PD;
  const size_t kb = qb + (size_t)D_ * NGP;
  const size_t vb = kb + (size_t)D_ * NGP;

  // Q row -> registers, pre-scaled
  float qreg[HDD];
  #pragma unroll
  for (int hd = 0; hd < HDD; ++hd)
    qreg[hd] = qkv[qb + (size_t)hd * NGP + t] * SCALE;

  // Runtime mask-dtype detect: int32 {0,1} words vs packed bool bytes.
  const unsigned* mw = (const unsigned*)mask;
  bool i32 = true;
  #pragma unroll
  for (int i = 0; i < 16; ++i) i32 = i32 && (mw[i] <= 1u);

  unsigned mbits[8];
  if (i32) {
    const unsigned* mr = mw + ((size_t)g * PD + t) * PD;
    #pragma unroll
    for (int w = 0; w < 8; ++w) {
      unsigned bits = 0;
      for (int j = 0; j < 32; ++j) bits |= (mr[w*32+j] ? 1u : 0u) << j;
      mbits[w] = bits;
    }
  } else {
    const unsigned* mr = (const unsigned*)(mask + ((size_t)g * PD + t) * PD);
    #pragma unroll
    for (int w = 0; w < 8; ++w) {
      unsigned bits = 0;
      for (int j = 0; j < 8; ++j) {
        unsigned v = mr[w*8+j];
        if (v & 0x000000FFu) bits |= 1u << (j*4+0);
        if (v & 0x0000FF00u) bits |= 1u << (j*4+1);
        if (v & 0x00FF0000u) bits |= 1u << (j*4+2);
        if (v & 0xFF000000u) bits |= 1u << (j*4+3);
      }
      mbits[w] = bits;
    }
  }

  float mx = -FLT_MAX, l = 0.f;
  float acc[HDD] = {};
  for (int c = 0; c < 4; ++c) {          // K/V chunks of 64 keys
    __syncthreads();
    {
      const int qq = t & 63, hq = t >> 6;
      #pragma unroll
      for (int hh = 0; hh < 16; ++hh) {
        int hd = hq * 16 + hh;
        k_s[qq][hd] = qkv[kb + (size_t)hd * NGP + c*64 + qq];
        v_s[qq][hd] = qkv[vb + (size_t)hd * NGP + c*64 + qq];
      }
    }
    __syncthreads();
    for (int ql = 0; ql < 64; ++ql) {
      const int qi = c*64 + ql;
      if (!((mbits[qi >> 5] >> (qi & 31)) & 1u)) continue;
      const float* kr = k_s[ql];
      float s0=0.f, s1=0.f, s2=0.f, s3=0.f;   // 4 chains to break FMA latency
      #pragma unroll
      for (int hd = 0; hd < HDD; hd += 4) {
        s0 = fmaf(qreg[hd+0], kr[hd+0], s0);
        s1 = fmaf(qreg[hd+1], kr[hd+1], s1);
        s2 = fmaf(qreg[hd+2], kr[hd+2], s2);
        s3 = fmaf(qreg[hd+3], kr[hd+3], s3);
      }
      float s = (s0+s1)+(s2+s3);
      const float* vr = v_s[ql];
      if (s <= mx) {                      // common path: no rescale of acc
        float pw = __expf(s - mx);
        l += pw;
        #pragma unroll
        for (int hd = 0; hd < HDD; ++hd) acc[hd] = fmaf(pw, vr[hd], acc[hd]);
      } else {                            // new max: exp(mx-s) underflows to 0 on first hit -> correct init
        float al = __expf(mx - s);
        l = fmaf(l, al, 1.f);
        #pragma unroll
        for (int hd = 0; hd < HDD; ++hd) acc[hd] = fmaf(acc[hd], al, vr[hd]);
        mx = s;
      }
    }
  }
  const float inv = 1.f / l;
  const size_t ob = (size_t)(h * HDD) * NGP + (size_t)g * PD;
  #pragma unroll
  for (int hd = 0; hd < HDD; ++hd)
    attn_out[ob + (size_t)hd * NGP + t] = acc[hd] * inv;
}

extern "C" void kernel_launch(void* const* d_in, const int* in_sizes, int n_in,
                              void* d_out, int out_size, void* d_ws, size_t ws_size,
                              hipStream_t stream) {
  const float* x      = (const float*)d_in[0];
  const unsigned char* mask = (const unsigned char*)d_in[1];
  const float* w_qkv  = (const float*)d_in[2];
  const float* w_proj = (const float*)d_in[3];
  const float* b_proj = (const float*)d_in[4];
  float* out = (float*)d_out;

  float* qkv_ws  = (float*)d_ws;                         // 3*768*16384 fp32 = 151 MB
  float* attn_ws = qkv_ws + (size_t)3 * D_ * NGP;        // 768*16384 fp32  =  50 MB

  for (int b = 0; b < 4; ++b) {
    const float* xb = x + (size_t)b * D_ * NGP;
    float* ob = out + (size_t)b * D_ * NGP;
    gemm_k<0><<<dim3(NGP/64, (3*D_)/64), 256, 0, stream>>>(w_qkv, xb, nullptr, qkv_ws, 3*D_, NGP, D_);
    attn_k  <<<dim3(GD, HH),            256, 0, stream>>>(qkv_ws, mask, attn_ws);
    gemm_k<1><<<dim3(NGP/64, D_/64),    256, 0, stream>>>(w_proj, attn_ws, b_proj, ob, D_, NGP, D_);
  }
}

// Round 2
// 2482.207 us; speedup vs baseline: 2.5697x; 2.5697x over previous
//
#include <hip/hip_runtime.h>
#include <float.h>

#define D_    768
#define GD    64
#define PD    256
#define HH    12
#define HDD   64
#define NGP   (GD*PD)   // 16384
#define SCALE 0.125f

typedef __bf16 bf16x8 __attribute__((ext_vector_type(8)));
typedef __bf16 bf16x4 __attribute__((ext_vector_type(4)));
typedef float  f32x4  __attribute__((ext_vector_type(4)));

__device__ __forceinline__ void gload_lds16(const __bf16* g, __bf16* l) {
  __builtin_amdgcn_global_load_lds(
      (const __attribute__((address_space(1))) void*)g,
      (__attribute__((address_space(3))) void*)l, 16, 0, 0);
}

__device__ __forceinline__ unsigned short f2bf_bits(float f) {
  __bf16 h = (__bf16)f;
  unsigned short u;
  __builtin_memcpy(&u, &h, 2);
  return u;
}

// ---------------- fp32 -> bf16 elementwise cast (weights) ----------------
__global__ void wcast_k(const float* __restrict__ in, __bf16* __restrict__ out, int n) {
  int i = (blockIdx.x * 256 + threadIdx.x) * 4;
  if (i >= n) return;
  float4 v = *(const float4*)(in + i);
  bf16x4 o;
  o[0] = (__bf16)v.x; o[1] = (__bf16)v.y; o[2] = (__bf16)v.z; o[3] = (__bf16)v.w;
  *(bf16x4*)(out + i) = o;
}

// ---------------- transpose-cast: in[768][16384] f32 -> out[16384][768] bf16 ----------------
__global__ void tcast_k(const float* __restrict__ in, __bf16* __restrict__ out) {
  __shared__ float s[32][66];           // 64-col tile needs [32][>=64]; 66 keeps reads ~conflict-free
  const int tid = threadIdx.x;
  const int c0 = blockIdx.x * 64;       // in-col base (out-row base)
  const int r0 = blockIdx.y * 32;       // in-row base
  const int lx = tid & 63, ly = tid >> 6;            // read: 4 rows/pass
  #pragma unroll
  for (int rr = 0; rr < 32; rr += 4)
    s[rr + ly][lx] = in[(size_t)(r0 + rr + ly) * NGP + c0 + lx];
  __syncthreads();
  const int wx = tid & 15, wy = tid >> 4;            // write: 16 out-rows/pass
  unsigned* outu = (unsigned*)out;
  #pragma unroll
  for (int p = 0; p < 64; p += 16) {
    int j = p + wy;                                  // out row = c0 + j
    unsigned pk = (unsigned)f2bf_bits(s[2*wx][j]) |
                  ((unsigned)f2bf_bits(s[2*wx+1][j]) << 16);
    outu[(size_t)(c0 + j) * (D_/2) + (r0 >> 1) + wx] = pk;
  }
}

// ---------------- MFMA GEMM: C[M,N] = A[M,K] * Bt[N,K]^T (+bias) ----------------
// 128x128 tile, 256 threads = 4 waves (2x2), 4x4 frags of 16x16x32 bf16 per wave, BK=32.
// LDS layout: 8 row-groups of 16 rows; group r at offset r*1KB; within group,
// 16B chunk s holds rows m=(s&15), k-chunk (s>>4) -> fragment read = lane-linear ds_read_b128.
template<int BIAS, int OUT_BF16>
__global__ __launch_bounds__(256, 2)
void mfma_gemm(const __bf16* __restrict__ A, const __bf16* __restrict__ Bt,
               const float* __restrict__ bias, void* __restrict__ Cout,
               int M, int N, int K) {
  __shared__ __align__(16) __bf16 As[128 * 32];
  __shared__ __align__(16) __bf16 Bs[128 * 32];
  const int tid = threadIdx.x;
  const int wave = tid >> 6, lane = tid & 63;
  const int wm = wave >> 1, wn = wave & 1;
  const int m0 = blockIdx.y * 128, n0 = blockIdx.x * 128;

  const int r0g = wave * 2, r1g = wave * 2 + 1;      // this wave's two staging groups
  const int kch = (lane >> 4) * 8;                   // k offset within 32-chunk
  const __bf16* gA0 = A  + (size_t)(m0 + r0g * 16 + (lane & 15)) * K + kch;
  const __bf16* gA1 = gA0 + (size_t)16 * K;
  const __bf16* gB0 = Bt + (size_t)(n0 + r0g * 16 + (lane & 15)) * K + kch;
  const __bf16* gB1 = gB0 + (size_t)16 * K;
  __bf16* lA0 = As + r0g * 512;  __bf16* lA1 = As + r1g * 512;
  __bf16* lB0 = Bs + r0g * 512;  __bf16* lB1 = Bs + r1g * 512;

  f32x4 acc[4][4] = {};
  const bf16x8* Av = (const bf16x8*)As;
  const bf16x8* Bv = (const bf16x8*)Bs;

  for (int k0 = 0; k0 < K; k0 += 32) {
    __syncthreads();                 // previous iter's LDS reads complete
    gload_lds16(gA0, lA0); gload_lds16(gA1, lA1);
    gload_lds16(gB0, lB0); gload_lds16(gB1, lB1);
    gA0 += 32; gA1 += 32; gB0 += 32; gB1 += 32;
    __syncthreads();                 // drains vmcnt(0): LDS tiles ready
    bf16x8 af[4], bf[4];
    #pragma unroll
    for (int i = 0; i < 4; ++i) af[i] = Av[(wm * 4 + i) * 64 + lane];
    #pragma unroll
    for (int j = 0; j < 4; ++j) bf[j] = Bv[(wn * 4 + j) * 64 + lane];
    #pragma unroll
    for (int i = 0; i < 4; ++i)
      #pragma unroll
      for (int j = 0; j < 4; ++j)
        acc[i][j] = __builtin_amdgcn_mfma_f32_16x16x32_bf16(af[i], bf[j], acc[i][j], 0, 0, 0);
  }

  // epilogue: D row=(lane>>4)*4+reg, col=lane&15
  #pragma unroll
  for (int i = 0; i < 4; ++i) {
    #pragma unroll
    for (int j = 0; j < 4; ++j) {
      const int col  = n0 + wn * 64 + j * 16 + (lane & 15);
      const int row0 = m0 + wm * 64 + i * 16 + (lane >> 4) * 4;
      #pragma unroll
      for (int r = 0; r < 4; ++r) {
        float v = acc[i][j][r];
        if (BIAS) v += bias[row0 + r];
        if (OUT_BF16)
          ((__bf16*)Cout)[(size_t)(row0 + r) * N + col] = (__bf16)v;
        else
          ((float*)Cout)[(size_t)(row0 + r) * N + col] = v;
      }
    }
  }
}

// ---------------- Attention: one block per (g,h); thread t = query row p ----------------
// qkv bf16 [2304][16384]; writes aot bf16 [16384][768] (transposed for proj GEMM).
__global__ __launch_bounds__(256, 1)
void attn_k(const __bf16* __restrict__ qkv, const unsigned char* __restrict__ mask,
            __bf16* __restrict__ aot) {
  __shared__ __align__(16) float k_s[64][68];   // row stride 272B: float4-aligned
  __shared__ __align__(16) float v_s[64][68];
  const int g = blockIdx.x, h = blockIdx.y;
  const int t = threadIdx.x;  // p
  const size_t qb = (size_t)(h * HDD) * NGP + (size_t)g * PD;
  const size_t kb = qb + (size_t)D_ * NGP;
  const size_t vb = kb + (size_t)D_ * NGP;

  float qreg[HDD];
  #pragma unroll
  for (int hd = 0; hd < HDD; ++hd)
    qreg[hd] = (float)qkv[qb + (size_t)hd * NGP + t] * SCALE;

  // mask dtype detect: int32 {0,1} words vs packed bool bytes
  const unsigned* mw = (const unsigned*)mask;
  bool i32 = true;
  #pragma unroll
  for (int i = 0; i < 16; ++i) i32 = i32 && (mw[i] <= 1u);

  unsigned mbits[8];
  if (i32) {
    const unsigned* mr = mw + ((size_t)g * PD + t) * PD;
    #pragma unroll
    for (int w = 0; w < 8; ++w) {
      unsigned bits = 0;
      for (int j = 0; j < 32; ++j) bits |= (mr[w*32+j] ? 1u : 0u) << j;
      mbits[w] = bits;
    }
  } else {
    const unsigned* mr = (const unsigned*)(mask + ((size_t)g * PD + t) * PD);
    #pragma unroll
    for (int w = 0; w < 8; ++w) {
      unsigned bits = 0;
      for (int j = 0; j < 8; ++j) {
        unsigned v = mr[w*8+j];
        if (v & 0x000000FFu) bits |= 1u << (j*4+0);
        if (v & 0x0000FF00u) bits |= 1u << (j*4+1);
        if (v & 0x00FF0000u) bits |= 1u << (j*4+2);
        if (v & 0xFF000000u) bits |= 1u << (j*4+3);
      }
      mbits[w] = bits;
    }
  }

  float mx = -FLT_MAX, l = 0.f;
  float acc[HDD] = {};
  for (int c = 0; c < 4; ++c) {
    __syncthreads();
    {
      const int qq = t & 63, hq = t >> 6;
      #pragma unroll
      for (int hh = 0; hh < 16; ++hh) {
        int hd = hq * 16 + hh;
        k_s[qq][hd] = (float)qkv[kb + (size_t)hd * NGP + c*64 + qq];
        v_s[qq][hd] = (float)qkv[vb + (size_t)hd * NGP + c*64 + qq];
      }
    }
    __syncthreads();
    for (int ql = 0; ql < 64; ++ql) {
      const int qi = c*64 + ql;
      if (!((mbits[qi >> 5] >> (qi & 31)) & 1u)) continue;
      const float4* kr4 = (const float4*)&k_s[ql][0];
      float s0=0.f, s1=0.f, s2=0.f, s3=0.f;
      #pragma unroll
      for (int q4 = 0; q4 < 16; ++q4) {
        float4 kv = kr4[q4];
        s0 = fmaf(qreg[q4*4+0], kv.x, s0);
        s1 = fmaf(qreg[q4*4+1], kv.y, s1);
        s2 = fmaf(qreg[q4*4+2], kv.z, s2);
        s3 = fmaf(qreg[q4*4+3], kv.w, s3);
      }
      float s = (s0+s1)+(s2+s3);
      const float4* vr4 = (const float4*)&v_s[ql][0];
      if (s <= mx) {
        float pw = __expf(s - mx);
        l += pw;
        #pragma unroll
        for (int q4 = 0; q4 < 16; ++q4) {
          float4 vv = vr4[q4];
          acc[q4*4+0] = fmaf(pw, vv.x, acc[q4*4+0]);
          acc[q4*4+1] = fmaf(pw, vv.y, acc[q4*4+1]);
          acc[q4*4+2] = fmaf(pw, vv.z, acc[q4*4+2]);
          acc[q4*4+3] = fmaf(pw, vv.w, acc[q4*4+3]);
        }
      } else {
        float al = __expf(mx - s);
        l = fmaf(l, al, 1.f);
        #pragma unroll
        for (int q4 = 0; q4 < 16; ++q4) {
          float4 vv = vr4[q4];
          acc[q4*4+0] = fmaf(acc[q4*4+0], al, vv.x);
          acc[q4*4+1] = fmaf(acc[q4*4+1], al, vv.y);
          acc[q4*4+2] = fmaf(acc[q4*4+2], al, vv.z);
          acc[q4*4+3] = fmaf(acc[q4*4+3], al, vv.w);
        }
        mx = s;
      }
    }
  }
  const float inv = 1.f / l;
  __bf16* aop = aot + ((size_t)(g * PD + t) * D_ + h * HDD);
  #pragma unroll
  for (int r8 = 0; r8 < 8; ++r8) {
    bf16x8 v;
    #pragma unroll
    for (int e = 0; e < 8; ++e) v[e] = (__bf16)(acc[r8*8+e] * inv);
    *(bf16x8*)(aop + r8*8) = v;
  }
}

extern "C" void kernel_launch(void* const* d_in, const int* in_sizes, int n_in,
                              void* d_out, int out_size, void* d_ws, size_t ws_size,
                              hipStream_t stream) {
  const float* x      = (const float*)d_in[0];
  const unsigned char* mask = (const unsigned char*)d_in[1];
  const float* w_qkv  = (const float*)d_in[2];
  const float* w_proj = (const float*)d_in[3];
  const float* b_proj = (const float*)d_in[4];
  float* out = (float*)d_out;

  // workspace layout (bf16 elements unless noted), total ~131 MB
  char* ws = (char*)d_ws;
  __bf16* qkv_bf = (__bf16*)ws;                       ws += (size_t)3*D_*NGP*2;  // 75.5 MB
  __bf16* xt     = (__bf16*)ws;                       ws += (size_t)NGP*D_*2;    // 25.2 MB
  __bf16* aot    = (__bf16*)ws;                       ws += (size_t)NGP*D_*2;    // 25.2 MB
  __bf16* wq_bf  = (__bf16*)ws;                       ws += (size_t)3*D_*D_*2;   //  3.5 MB
  __bf16* wp_bf  = (__bf16*)ws;                                                  //  1.2 MB

  wcast_k<<<(3*D_*D_)/1024, 256, 0, stream>>>(w_qkv,  wq_bf, 3*D_*D_);
  wcast_k<<<(D_*D_)/1024,   256, 0, stream>>>(w_proj, wp_bf, D_*D_);

  for (int b = 0; b < 4; ++b) {
    const float* xb = x + (size_t)b * D_ * NGP;
    float* ob = out + (size_t)b * D_ * NGP;
    tcast_k<<<dim3(NGP/64, D_/32), 256, 0, stream>>>(xb, xt);
    mfma_gemm<0,1><<<dim3(NGP/128, (3*D_)/128), 256, 0, stream>>>(wq_bf, xt, nullptr, qkv_bf, 3*D_, NGP, D_);
    attn_k<<<dim3(GD, HH), 256, 0, stream>>>(qkv_bf, mask, aot);
    mfma_gemm<1,0><<<dim3(NGP/128, D_/128), 256, 0, stream>>>(wp_bf, aot, b_proj, ob, D_, NGP, D_);
  }
}